// Round 10
// baseline (115.545 us; speedup 1.0000x reference)
//
#include <hip/hip_runtime.h>
#include <hip/hip_bf16.h>

#define BATCH 16384
#define DIM   512
#define UNITS 1024
// GAMMA = 0.5 folded into epilogue: out = exp(cross - 0.5*xsq - 0.5*musq)

typedef float v16f __attribute__((ext_vector_type(16)));

#define APITCH 516   // fp32 LDS pitch (floats) for prep-A transpose reads
#define BPITCH 33

__device__ __forceinline__ void async_copy16(const void* g, void* l) {
    __builtin_amdgcn_global_load_lds(
        (const __attribute__((address_space(1))) void*)g,
        (__attribute__((address_space(3))) void*)l,
        16 /*bytes*/, 0 /*offset*/, 0 /*aux*/);
}

// Fragment-order prep (fp8 e4m3), xsq/musq on ORIGINAL fp32 values.
// A8f: byte ((chunk*32 + kw)*64 + lane)*8 — lane l holds
//   A[chunk*32 + (l&31)][kw*16 + (l>>5)*8 + 0..7].
// B8f: byte ((ng*32 + kw)*64 + lane)*8 — lane l holds
//   B[kw*16 + (l>>5)*8 + 0..7][ng*32 + (l&31)].
// Blocks 0..31: B path (first; latency-bound). Blocks 32..543: A path,
// chunk c = ((b-32)&7)*64 + ((b-32)>>3) -> chunk c converted on XCD c/64,
// the same XCD whose GEMM blocks read it.
__global__ __launch_bounds__(256)
void prep_kernel(const float* __restrict__ in, const float* __restrict__ mu,
                 unsigned char* __restrict__ A8f, unsigned char* __restrict__ B8f,
                 float* __restrict__ xsq, float* __restrict__ musq) {
    __shared__ __attribute__((aligned(16))) char smem[512 * BPITCH * 4 + 1024];
    const int t  = threadIdx.x;
    const int l  = t & 63, w = t >> 6;
    const int ln = l & 31, h = l >> 5;

    if (blockIdx.x >= UNITS / 32) {
        // ---- A path: one block per 32-row chunk, XCD-matched to the GEMM ----
        float* lds = (float*)smem;                       // [32][APITCH]
        float* red = (float*)(smem + 32 * APITCH * 4);   // [32][8]
        const int bb = blockIdx.x - UNITS / 32;
        const int c  = (bb & 7) * 64 + (bb >> 3);        // chunk 0..511
        const float4* src = (const float4*)(in + (size_t)c * 32 * DIM);
        float4* l4 = (float4*)lds;
#pragma unroll
        for (int i = 0; i < 16; i++) {
            const int f = i * 256 + t;                   // float4 id 0..4095
            l4[(f >> 7) * (APITCH / 4) + (f & 127)] = src[f];
        }
        __syncthreads();
        float s = 0.f;
#pragma unroll
        for (int j = 0; j < 8; j++) {
            const int kw = w * 8 + j;
            const float* p = lds + ln * APITCH + kw * 16 + h * 8;
            float4 f0 = *(const float4*)p;
            float4 f1 = *(const float4*)(p + 4);
            s += f0.x * f0.x + f0.y * f0.y + f0.z * f0.z + f0.w * f0.w
               + f1.x * f1.x + f1.y * f1.y + f1.z * f1.z + f1.w * f1.w;
            int lo = __builtin_amdgcn_cvt_pk_fp8_f32(f0.x, f0.y, 0, false);
            lo     = __builtin_amdgcn_cvt_pk_fp8_f32(f0.z, f0.w, lo, true);
            int hi = __builtin_amdgcn_cvt_pk_fp8_f32(f1.x, f1.y, 0, false);
            hi     = __builtin_amdgcn_cvt_pk_fp8_f32(f1.z, f1.w, hi, true);
            *(int2*)(A8f + (((size_t)c * 32 + kw) * 64 + l) * 8) = make_int2(lo, hi);
        }
        red[ln * 8 + w * 2 + h] = s;
        __syncthreads();
        if (t < 32) {
            float a = 0.f;
#pragma unroll
            for (int i = 0; i < 8; i++) a += red[t * 8 + i];
            xsq[c * 32 + t] = a;
        }
    } else {
        // ---- B path: one block per 32-column group ----
        float* lds = (float*)smem;                       // [512][BPITCH]
        float* red = (float*)(smem + 512 * BPITCH * 4);  // [32][8]
        const int nb = blockIdx.x;
        const int n0 = nb * 32;
        const int col = t & 31, kg = t >> 5;
        float s = 0.f;
        for (int i = 0; i < 64; i++) {
            const int k = i * 8 + kg;
            float v = mu[(size_t)k * UNITS + n0 + col];
            s += v * v;
            lds[k * BPITCH + col] = v;
        }
        red[col * 8 + kg] = s;
        __syncthreads();
        if (t < 32) {
            float a = 0.f;
#pragma unroll
            for (int i = 0; i < 8; i++) a += red[t * 8 + i];
            musq[n0 + t] = a;
        }
#pragma unroll
        for (int j = 0; j < 8; j++) {
            const int kw = w * 8 + j;
            const float* p = lds + (kw * 16 + h * 8) * BPITCH + ln;
            float f[8];
#pragma unroll
            for (int i = 0; i < 8; i++) f[i] = p[i * BPITCH];
            int lo = __builtin_amdgcn_cvt_pk_fp8_f32(f[0], f[1], 0, false);
            lo     = __builtin_amdgcn_cvt_pk_fp8_f32(f[2], f[3], lo, true);
            int hi = __builtin_amdgcn_cvt_pk_fp8_f32(f[4], f[5], 0, false);
            hi     = __builtin_amdgcn_cvt_pk_fp8_f32(f[6], f[7], hi, true);
            *(int2*)(B8f + (((size_t)nb * 32 + kw) * 64 + l) * 8) = make_int2(lo, hi);
        }
    }
}

// RBF GEMM, 512 blocks x 512 threads (8 waves), 2 blocks/CU -> block-level
// phase overlap (one block's B-stage drain / store tail hides under the
// other's MFMA). Block tile 256M x 128N; B-tile 64 KB LDS, staged in two
// 32 KB K-halves: stage(0) -> barrier -> issue stage(1) async -> MFMA
// half-0 (stage-1 copies fly underneath) -> barrier -> MFMA half-1.
// LDS layout [g][kw][512B] is linear in chunk id within each g; waves never
// straddle a g boundary, so global_load_lds lane-linearity holds.
// kw-loop: 2 A global b64 (coalesced 512 B) + 2 LDS b64 (2-way, free) +
// 4 MFMAs. XCD x owns m-tiles [x*8, x*8+8) -> A L2-local, 8x reuse.
__global__ __launch_bounds__(512, 4)
void rbf_gemm_kernel(const unsigned char* __restrict__ A8f,
                     const unsigned char* __restrict__ B8f,
                     const float* __restrict__ xsq,
                     const float* __restrict__ musq,
                     float* __restrict__ out) {
    __shared__ __attribute__((aligned(16))) unsigned char Bs[65536]; // 64 KB

    const int t  = threadIdx.x;
    const int l  = t & 63;
    const int w  = t >> 6;          // wave 0..7
    const int ln = l & 31;
    const int h  = l >> 5;

    const int b  = blockIdx.x;      // 0..511
    const int x  = b & 7;           // XCD (round-robin dispatch)
    const int j  = b >> 3;          // 0..63
    const int mt = x * 8 + (j & 7); // m-tile 0..63 (256 rows)
    const int nt = j >> 3;          // n-tile 0..7  (128 cols)
    const int m0 = mt * 256;
    const int n0 = nt * 128;
    const int wm = (w >> 1) * 64;   // wave row origin in tile
    const int wn = (w & 1) * 64;    // wave col origin in tile
    const int ng0 = n0 >> 5;        // first of 4 B-groups in tile

    // ---- staging: half hf covers kw [hf*16, hf*16+16), 2048 x 16B chunks.
    // chunk c: g = c>>9, kwl = (c>>5)&15, byte = (c&31)*16.
#define STAGE(hf)                                                           \
    {                                                                       \
        _Pragma("unroll")                                                   \
        for (int i = 0; i < 4; i++) {                                       \
            const int c   = i * 512 + t;                                    \
            const int g   = c >> 9;                                         \
            const int kwl = (c >> 5) & 15;                                  \
            const int byt = (c & 31) * 16;                                  \
            async_copy16(                                                   \
                B8f + ((size_t)(ng0 + g) * 32 + (hf) * 16 + kwl) * 512 + byt, \
                Bs + ((g * 32 + (hf) * 16 + kwl) * 512 + byt));             \
        }                                                                   \
    }

    STAGE(0);
    __syncthreads();
    STAGE(1);                       // flies under half-0 compute

    const long* Af0 = (const long*)(A8f + (size_t)((m0 + wm) >> 5) * 16384) + l;
    const long* Af1 = Af0 + 2048;   // next 32-row chunk
    const long* Bl0 = (const long*)(Bs + (wn >> 5) * 16384) + l;
    const long* Bl1 = Bl0 + 2048;   // next 32-col group

    v16f acc[2][2];
#pragma unroll
    for (int c = 0; c < 2; c++)
#pragma unroll
        for (int g = 0; g < 2; g++) acc[c][g] = (v16f)0.f;

#pragma unroll 4
    for (int kw = 0; kw < 16; kw++) {
        long a0 = Af0[kw * 64];
        long a1 = Af1[kw * 64];
        long b0 = Bl0[kw * 64];
        long b1 = Bl1[kw * 64];
        acc[0][0] = __builtin_amdgcn_mfma_f32_32x32x16_fp8_fp8(a0, b0, acc[0][0], 0, 0, 0);
        acc[0][1] = __builtin_amdgcn_mfma_f32_32x32x16_fp8_fp8(a0, b1, acc[0][1], 0, 0, 0);
        acc[1][0] = __builtin_amdgcn_mfma_f32_32x32x16_fp8_fp8(a1, b0, acc[1][0], 0, 0, 0);
        acc[1][1] = __builtin_amdgcn_mfma_f32_32x32x16_fp8_fp8(a1, b1, acc[1][1], 0, 0, 0);
    }
    __syncthreads();                // drains stage(1)
#pragma unroll 4
    for (int kw = 16; kw < 32; kw++) {
        long a0 = Af0[kw * 64];
        long a1 = Af1[kw * 64];
        long b0 = Bl0[kw * 64];
        long b1 = Bl1[kw * 64];
        acc[0][0] = __builtin_amdgcn_mfma_f32_32x32x16_fp8_fp8(a0, b0, acc[0][0], 0, 0, 0);
        acc[0][1] = __builtin_amdgcn_mfma_f32_32x32x16_fp8_fp8(a0, b1, acc[0][1], 0, 0, 0);
        acc[1][0] = __builtin_amdgcn_mfma_f32_32x32x16_fp8_fp8(a1, b0, acc[1][0], 0, 0, 0);
        acc[1][1] = __builtin_amdgcn_mfma_f32_32x32x16_fp8_fp8(a1, b1, acc[1][1], 0, 0, 0);
    }

    // ---- Epilogue. C/D layout (m74/m101, dtype-indep): col = l&31,
    // row = (reg&3) + 8*(reg>>2) + 4*(l>>5). ----
#pragma unroll
    for (int c = 0; c < 2; c++) {
        const int mc = m0 + wm + c * 32;
        const float xv = -0.5f * xsq[mc + ln];     // lane ln holds row mc+ln
#pragma unroll
        for (int g = 0; g < 2; g++) {
            const int nc = n0 + wn + g * 32;
            const float mb = -0.5f * musq[nc + ln];
#pragma unroll
            for (int r = 0; r < 16; r++) {
                const int rl = (r & 3) + 8 * (r >> 2) + 4 * h;
                const float xb = __shfl(xv, rl, 64);
                float v = __expf(acc[c][g][r] + xb + mb);
                __builtin_nontemporal_store(
                    v, out + (size_t)(mc + rl) * UNITS + nc + ln);
            }
        }
    }
#undef STAGE
}

extern "C" void kernel_launch(void* const* d_in, const int* in_sizes, int n_in,
                              void* d_out, int out_size, void* d_ws, size_t ws_size,
                              hipStream_t stream) {
    const float* inputs = (const float*)d_in[0];   // [16384, 512] fp32
    const float* mu     = (const float*)d_in[1];   // [512, 1024] fp32
    float* out = (float*)d_out;                    // [16384, 1024] fp32

    char* ws = (char*)d_ws;
    unsigned char* A8f = (unsigned char*)ws;                           // 8 MiB
    unsigned char* B8f = (unsigned char*)(ws + (size_t)BATCH * DIM);   // 512 KiB
    float* xsq  = (float*)(ws + (size_t)BATCH * DIM + (size_t)UNITS * DIM);
    float* musq = xsq + BATCH;

    prep_kernel<<<UNITS / 32 + BATCH / 32, 256, 0, stream>>>(
        inputs, mu, A8f, B8f, xsq, musq);
    rbf_gemm_kernel<<<512, 512, 0, stream>>>(A8f, B8f, xsq, musq, out);
}